// Round 2
// baseline (656.824 us; speedup 1.0000x reference)
//
#include <hip/hip_runtime.h>
#include <hip/hip_bf16.h>
#include <math.h>

#define NNODES 100000

// ---------------------------------------------------------------- utilities
__device__ __forceinline__ int edge_val(const void* eidx, int is64, size_t i) {
  if (is64) return (int)((const long long*)eidx)[i];
  return ((const int*)eidx)[i];
}

// Detect whether edge_index buffer is int64 or int32.
__global__ void k_detect(const void* eidx, int* flag) {
  int t = threadIdx.x;  // 64 threads, one wave
  int bad = 0;
  const unsigned long long* p = (const unsigned long long*)eidx;
  for (int i = t; i < 1024; i += 64)
    if (p[i] >> 32) bad = 1;
  unsigned long long b = __ballot(bad);
  if (t == 0) flag[0] = (b == 0ULL) ? 1 : 0;
}

// ---------------------------------------------------------------- degree
__global__ void k_count(const void* eidx, const int* __restrict__ flag,
                        int* __restrict__ cnt, int E) {
  int e = blockIdx.x * blockDim.x + threadIdx.x;
  if (e >= E) return;
  int is64 = flag[0];
  int d = edge_val(eidx, is64, (size_t)E + e);
  atomicAdd(&cnt[d], 1);
}

__global__ void k_dis(const int* __restrict__ cnt, float* __restrict__ dis, int n) {
  int i = blockIdx.x * blockDim.x + threadIdx.x;
  if (i < n) dis[i] = rsqrtf((float)(cnt[i] + 1));  // +1 = self loop
}

// ---------------------------------------------------------------- scan (3 kernels)
__global__ void k_scan_reduce(const int* __restrict__ cnt, int* __restrict__ bsum, int n) {
  int idx = blockIdx.x * 256 + threadIdx.x;
  int v = (idx < n) ? cnt[idx] : 0;
  #pragma unroll
  for (int d = 32; d > 0; d >>= 1) v += __shfl_down(v, d);
  __shared__ int ws4[4];
  if ((threadIdx.x & 63) == 0) ws4[threadIdx.x >> 6] = v;
  __syncthreads();
  if (threadIdx.x == 0) bsum[blockIdx.x] = ws4[0] + ws4[1] + ws4[2] + ws4[3];
}

// single block: inclusive scan of nb block sums -> exclusive in-place; total -> rowptr[n]
__global__ void k_scan_partials(int* bsum, int nb, int* rowptr, int n) {
  __shared__ int s[512];
  int t = threadIdx.x;  // 512 threads, nb <= 512
  int v = (t < nb) ? bsum[t] : 0;
  s[t] = v;
  __syncthreads();
  for (int d = 1; d < 512; d <<= 1) {
    int u = (t >= d) ? s[t - d] : 0;
    __syncthreads();
    s[t] += u;
    __syncthreads();
  }
  if (t < nb) bsum[t] = (t == 0) ? 0 : s[t - 1];
  if (t == 0) rowptr[n] = s[nb - 1];
}

__global__ void k_scan_final(const int* __restrict__ cnt, const int* __restrict__ bsum_ex,
                             int* __restrict__ rowptr, int* __restrict__ cursor, int n) {
  __shared__ int s[256];
  int t = threadIdx.x;
  int idx = blockIdx.x * 256 + t;
  int v = (idx < n) ? cnt[idx] : 0;
  s[t] = v;
  __syncthreads();
  for (int d = 1; d < 256; d <<= 1) {
    int u = (t >= d) ? s[t - d] : 0;
    __syncthreads();
    s[t] += u;
    __syncthreads();
  }
  if (idx < n) {
    int excl = bsum_ex[blockIdx.x] + s[t] - v;
    rowptr[idx] = excl;
    cursor[idx] = excl;
  }
}

// ---------------------------------------------------------------- CSR scatter
// col only — norm weights are factored into the pre-scaled features g = dis*h.
__global__ void k_scatter(const void* eidx, const int* __restrict__ flag,
                          int* __restrict__ cursor, int* __restrict__ col, int E) {
  int e = blockIdx.x * blockDim.x + threadIdx.x;
  if (e >= E) return;
  int is64 = flag[0];
  int s = edge_val(eidx, is64, e);
  int d = edge_val(eidx, is64, (size_t)E + e);
  int pos = atomicAdd(&cursor[d], 1);
  col[pos] = s;
}

// ---------------------------------------------------------------- GEMM (N=16)
// thread-per-row; W reads are wave-uniform -> scalar loads; epilogue scales by dis[row]
template <int K>
__global__ void k_gemm(const float* __restrict__ x, const float* __restrict__ W,
                       const float* __restrict__ dis, float* __restrict__ out, int nrows) {
  int row = blockIdx.x * blockDim.x + threadIdx.x;
  if (row >= nrows) return;
  const float4* xr = (const float4*)(x + (size_t)row * K);
  float acc[16];
  #pragma unroll
  for (int j = 0; j < 16; ++j) acc[j] = 0.f;
  #pragma unroll 2
  for (int k4 = 0; k4 < K / 4; ++k4) {
    float4 xv = xr[k4];
    const float* xs = (const float*)&xv;
    #pragma unroll
    for (int kk = 0; kk < 4; ++kk) {
      #pragma unroll
      for (int j = 0; j < 16; ++j)
        acc[j] = fmaf(xs[kk], W[(size_t)(k4 * 4 + kk) * 16 + j], acc[j]);
    }
  }
  float dd = dis[row];
  float4* o = (float4*)(out + (size_t)row * 16);
  #pragma unroll
  for (int q = 0; q < 4; ++q)
    o[q] = make_float4(acc[q * 4] * dd, acc[q * 4 + 1] * dd,
                       acc[q * 4 + 2] * dd, acc[q * 4 + 3] * dd);
}

// ---------------------------------------------------------------- aggregation
// wave per node; lane = (edge_slot 0..3, j 0..15)
// g = dis*h pre-scaled; out_j = act( dis[node]*(sum_e g[col[e]][j] + g[node][j]) + b[j] )
template <int MODE>
__global__ void k_agg(const float* __restrict__ g, const int* __restrict__ col,
                      const int* __restrict__ rowptr, const float* __restrict__ dis,
                      const float* __restrict__ bias, float* __restrict__ out) {
  int wid = threadIdx.x >> 6;
  int node = blockIdx.x * (blockDim.x >> 6) + wid;
  if (node >= NNODES) return;
  int lane = threadIdx.x & 63;
  int slot = lane >> 4;
  int j = lane & 15;
  int beg = rowptr[node], end = rowptr[node + 1];
  float acc = 0.f;
  for (int e = beg + slot; e < end; e += 4) {
    int s = col[e];
    acc += g[(size_t)s * 16 + j];
  }
  acc += __shfl_xor(acc, 16);
  acc += __shfl_xor(acc, 32);
  float z = dis[node] * (acc + g[(size_t)node * 16 + j]) + bias[j];
  if (MODE == 0) {
    z = fmaxf(z, 0.f);
    if (lane < 16) out[(size_t)node * 16 + j] = z;
  } else {
    float m = z;
    #pragma unroll
    for (int d = 1; d < 16; d <<= 1) m = fmaxf(m, __shfl_xor(m, d));
    float ex = expf(z - m);
    float sum = ex;
    #pragma unroll
    for (int d = 1; d < 16; d <<= 1) sum += __shfl_xor(sum, d);
    float r = z - m - logf(sum);
    if (lane < 16) out[(size_t)node * 16 + j] = r;
  }
}

// ---------------------------------------------------------------- launch
extern "C" void kernel_launch(void* const* d_in, const int* in_sizes, int n_in,
                              void* d_out, int out_size, void* d_ws, size_t ws_size,
                              hipStream_t stream) {
  const float* x  = (const float*)d_in[0];
  const void*  ei = d_in[1];
  const float* W1 = (const float*)d_in[2];
  const float* b1 = (const float*)d_in[3];
  const float* W2 = (const float*)d_in[4];
  const float* b2 = (const float*)d_in[5];
  float* out = (float*)d_out;

  const int n = NNODES;
  const int E = in_sizes[1] / 2;

  char* ws = (char*)d_ws;
  size_t off = 0;
  auto alloc = [&](size_t bytes) -> void* {
    void* p = ws + off;
    off = (off + bytes + 255) & ~(size_t)255;
    return p;
  };
  int*   flag   = (int*)  alloc(256);
  int*   cnt    = (int*)  alloc((size_t)n * 4);
  float* dis    = (float*)alloc((size_t)n * 4);
  int*   rowptr = (int*)  alloc((size_t)(n + 1) * 4);
  int*   cursor = (int*)  alloc((size_t)n * 4);
  int*   bsum   = (int*)  alloc(4096);
  int*   col    = (int*)  alloc((size_t)E * 4);
  float* g1     = (float*)alloc((size_t)n * 16 * 4);
  float* o1     = (float*)alloc((size_t)n * 16 * 4);
  float* g2     = (float*)alloc((size_t)n * 16 * 4);
  (void)ws_size; (void)n_in; (void)out_size;

  hipMemsetAsync(cnt, 0, (size_t)n * 4, stream);
  k_detect<<<1, 64, 0, stream>>>(ei, flag);
  k_count<<<(E + 255) / 256, 256, 0, stream>>>(ei, flag, cnt, E);
  k_dis<<<(n + 255) / 256, 256, 0, stream>>>(cnt, dis, n);

  // GEMM1 can start as soon as dis is ready (independent of scan/scatter)
  k_gemm<512><<<(n + 63) / 64, 64, 0, stream>>>(x, W1, dis, g1, n);

  int nb = (n + 255) / 256;  // 391 <= 512
  k_scan_reduce<<<nb, 256, 0, stream>>>(cnt, bsum, n);
  k_scan_partials<<<1, 512, 0, stream>>>(bsum, nb, rowptr, n);
  k_scan_final<<<nb, 256, 0, stream>>>(cnt, bsum, rowptr, cursor, n);

  k_scatter<<<(E + 255) / 256, 256, 0, stream>>>(ei, flag, cursor, col, E);

  k_agg<0><<<(n + 3) / 4, 256, 0, stream>>>(g1, col, rowptr, dis, b1, o1);
  k_gemm<16><<<(n + 63) / 64, 64, 0, stream>>>(o1, W2, dis, g2, n);
  k_agg<1><<<(n + 3) / 4, 256, 0, stream>>>(g2, col, rowptr, dis, b2, out);
}

// Round 3
// 520.965 us; speedup vs baseline: 1.2608x; 1.2608x over previous
//
#include <hip/hip_runtime.h>
#include <hip/hip_bf16.h>
#include <math.h>

#define NNODES 100000
#define NXCD 8
#define XRANGE 12500  // NNODES / NXCD exactly

// ---------------------------------------------------------------- utilities
__device__ __forceinline__ int edge_val(const void* eidx, int is64, size_t i) {
  if (is64) return (int)((const long long*)eidx)[i];
  return ((const int*)eidx)[i];
}

// Detect whether edge_index buffer is int64 or int32.
__global__ void k_detect(const void* eidx, int* flag) {
  int t = threadIdx.x;  // 64 threads, one wave
  int bad = 0;
  const unsigned long long* p = (const unsigned long long*)eidx;
  for (int i = t; i < 1024; i += 64)
    if (p[i] >> 32) bad = 1;
  unsigned long long b = __ballot(bad);
  if (t == 0) flag[0] = (b == 0ULL) ? 1 : 0;
}

// ---------------------------------------------------------------- degree
__global__ void k_count(const void* eidx, const int* __restrict__ flag,
                        int* __restrict__ cnt, int E) {
  int e = blockIdx.x * blockDim.x + threadIdx.x;
  if (e >= E) return;
  int is64 = flag[0];
  int d = edge_val(eidx, is64, (size_t)E + e);
  atomicAdd(&cnt[d], 1);
}

__global__ void k_dis(const int* __restrict__ cnt, float* __restrict__ dis, int n) {
  int i = blockIdx.x * blockDim.x + threadIdx.x;
  if (i < n) dis[i] = rsqrtf((float)(cnt[i] + 1));  // +1 = self loop
}

// ---------------------------------------------------------------- scan (3 kernels)
__global__ void k_scan_reduce(const int* __restrict__ cnt, int* __restrict__ bsum, int n) {
  int idx = blockIdx.x * 256 + threadIdx.x;
  int v = (idx < n) ? cnt[idx] : 0;
  #pragma unroll
  for (int d = 32; d > 0; d >>= 1) v += __shfl_down(v, d);
  __shared__ int ws4[4];
  if ((threadIdx.x & 63) == 0) ws4[threadIdx.x >> 6] = v;
  __syncthreads();
  if (threadIdx.x == 0) bsum[blockIdx.x] = ws4[0] + ws4[1] + ws4[2] + ws4[3];
}

// single block: inclusive scan of nb block sums -> exclusive in-place; total -> rowptr[n]
__global__ void k_scan_partials(int* bsum, int nb, int* rowptr, int n) {
  __shared__ int s[512];
  int t = threadIdx.x;  // 512 threads, nb <= 512
  int v = (t < nb) ? bsum[t] : 0;
  s[t] = v;
  __syncthreads();
  for (int d = 1; d < 512; d <<= 1) {
    int u = (t >= d) ? s[t - d] : 0;
    __syncthreads();
    s[t] += u;
    __syncthreads();
  }
  if (t < nb) bsum[t] = (t == 0) ? 0 : s[t - 1];
  if (t == 0) rowptr[n] = s[nb - 1];
}

__global__ void k_scan_final(const int* __restrict__ cnt, const int* __restrict__ bsum_ex,
                             int* __restrict__ rowptr, int* __restrict__ cursor, int n) {
  __shared__ int s[256];
  int t = threadIdx.x;
  int idx = blockIdx.x * 256 + t;
  int v = (idx < n) ? cnt[idx] : 0;
  s[t] = v;
  __syncthreads();
  for (int d = 1; d < 256; d <<= 1) {
    int u = (t >= d) ? s[t - d] : 0;
    __syncthreads();
    s[t] += u;
    __syncthreads();
  }
  if (idx < n) {
    int excl = bsum_ex[blockIdx.x] + s[t] - v;
    rowptr[idx] = excl;
    cursor[idx] = excl;
  }
}

// ---------------------------------------------------------------- CSR scatter
// XCD-partitioned by dst range: blockIdx.x & 7 round-robins over the 8 XCDs,
// so each XCD's col-write window (~1.6 MB) and cursor slice (50 KB) stay
// resident in ITS OWN L2 — no cross-XCD dirty-line sharing. The edge stream
// is re-read once per XCD but served by the shared 256 MiB L3.
// Correctness does not depend on the blockIdx->XCD mapping, only locality.
__global__ void k_scatter(const void* eidx, const int* __restrict__ flag,
                          int* __restrict__ cursor, int* __restrict__ col,
                          int E, int bpx) {
  int xcd = blockIdx.x & (NXCD - 1);
  int chunk = blockIdx.x >> 3;
  int lo = xcd * XRANGE;
  int hi = lo + XRANGE;
  int is64 = flag[0];
  int stride = bpx * blockDim.x;
  for (int e = chunk * blockDim.x + threadIdx.x; e < E; e += stride) {
    int d = edge_val(eidx, is64, (size_t)E + e);
    if (d >= lo && d < hi) {
      int s = edge_val(eidx, is64, e);
      int pos = atomicAdd(&cursor[d], 1);
      col[pos] = s;
    }
  }
}

// ---------------------------------------------------------------- GEMM (N=16)
// thread-per-row; W reads are wave-uniform -> scalar loads; epilogue scales by dis[row]
template <int K>
__global__ void k_gemm(const float* __restrict__ x, const float* __restrict__ W,
                       const float* __restrict__ dis, float* __restrict__ out, int nrows) {
  int row = blockIdx.x * blockDim.x + threadIdx.x;
  if (row >= nrows) return;
  const float4* xr = (const float4*)(x + (size_t)row * K);
  float acc[16];
  #pragma unroll
  for (int j = 0; j < 16; ++j) acc[j] = 0.f;
  #pragma unroll 2
  for (int k4 = 0; k4 < K / 4; ++k4) {
    float4 xv = xr[k4];
    const float* xs = (const float*)&xv;
    #pragma unroll
    for (int kk = 0; kk < 4; ++kk) {
      #pragma unroll
      for (int j = 0; j < 16; ++j)
        acc[j] = fmaf(xs[kk], W[(size_t)(k4 * 4 + kk) * 16 + j], acc[j]);
    }
  }
  float dd = dis[row];
  float4* o = (float4*)(out + (size_t)row * 16);
  #pragma unroll
  for (int q = 0; q < 4; ++q)
    o[q] = make_float4(acc[q * 4] * dd, acc[q * 4 + 1] * dd,
                       acc[q * 4 + 2] * dd, acc[q * 4 + 3] * dd);
}

// ---------------------------------------------------------------- aggregation
// wave per node; lane = (edge_slot 0..3, j 0..15)
// g = dis*h pre-scaled; out_j = act( dis[node]*(sum_e g[col[e]][j] + g[node][j]) + b[j] )
template <int MODE>
__global__ void k_agg(const float* __restrict__ g, const int* __restrict__ col,
                      const int* __restrict__ rowptr, const float* __restrict__ dis,
                      const float* __restrict__ bias, float* __restrict__ out) {
  int wid = threadIdx.x >> 6;
  int node = blockIdx.x * (blockDim.x >> 6) + wid;
  if (node >= NNODES) return;
  int lane = threadIdx.x & 63;
  int slot = lane >> 4;
  int j = lane & 15;
  int beg = rowptr[node], end = rowptr[node + 1];
  float acc = 0.f;
  for (int e = beg + slot; e < end; e += 4) {
    int s = col[e];
    acc += g[(size_t)s * 16 + j];
  }
  acc += __shfl_xor(acc, 16);
  acc += __shfl_xor(acc, 32);
  float z = dis[node] * (acc + g[(size_t)node * 16 + j]) + bias[j];
  if (MODE == 0) {
    z = fmaxf(z, 0.f);
    if (lane < 16) out[(size_t)node * 16 + j] = z;
  } else {
    float m = z;
    #pragma unroll
    for (int d = 1; d < 16; d <<= 1) m = fmaxf(m, __shfl_xor(m, d));
    float ex = expf(z - m);
    float sum = ex;
    #pragma unroll
    for (int d = 1; d < 16; d <<= 1) sum += __shfl_xor(sum, d);
    float r = z - m - logf(sum);
    if (lane < 16) out[(size_t)node * 16 + j] = r;
  }
}

// ---------------------------------------------------------------- launch
extern "C" void kernel_launch(void* const* d_in, const int* in_sizes, int n_in,
                              void* d_out, int out_size, void* d_ws, size_t ws_size,
                              hipStream_t stream) {
  const float* x  = (const float*)d_in[0];
  const void*  ei = d_in[1];
  const float* W1 = (const float*)d_in[2];
  const float* b1 = (const float*)d_in[3];
  const float* W2 = (const float*)d_in[4];
  const float* b2 = (const float*)d_in[5];
  float* out = (float*)d_out;

  const int n = NNODES;
  const int E = in_sizes[1] / 2;

  char* ws = (char*)d_ws;
  size_t off = 0;
  auto alloc = [&](size_t bytes) -> void* {
    void* p = ws + off;
    off = (off + bytes + 255) & ~(size_t)255;
    return p;
  };
  int*   flag   = (int*)  alloc(256);
  int*   cnt    = (int*)  alloc((size_t)n * 4);
  float* dis    = (float*)alloc((size_t)n * 4);
  int*   rowptr = (int*)  alloc((size_t)(n + 1) * 4);
  int*   cursor = (int*)  alloc((size_t)n * 4);
  int*   bsum   = (int*)  alloc(4096);
  int*   col    = (int*)  alloc((size_t)E * 4);
  float* g1     = (float*)alloc((size_t)n * 16 * 4);
  float* o1     = (float*)alloc((size_t)n * 16 * 4);
  float* g2     = (float*)alloc((size_t)n * 16 * 4);
  (void)ws_size; (void)n_in; (void)out_size;

  hipMemsetAsync(cnt, 0, (size_t)n * 4, stream);
  k_detect<<<1, 64, 0, stream>>>(ei, flag);
  k_count<<<(E + 255) / 256, 256, 0, stream>>>(ei, flag, cnt, E);
  k_dis<<<(n + 255) / 256, 256, 0, stream>>>(cnt, dis, n);

  // GEMM1 only needs dis — run it before the scan/scatter chain.
  k_gemm<512><<<(n + 63) / 64, 64, 0, stream>>>(x, W1, dis, g1, n);

  int nb = (n + 255) / 256;  // 391 <= 512
  k_scan_reduce<<<nb, 256, 0, stream>>>(cnt, bsum, n);
  k_scan_partials<<<1, 512, 0, stream>>>(bsum, nb, rowptr, n);
  k_scan_final<<<nb, 256, 0, stream>>>(cnt, bsum, rowptr, cursor, n);

  const int bpx = 96;  // blocks per XCD; grid = 8 * 96 = 768 blocks
  k_scatter<<<NXCD * bpx, 256, 0, stream>>>(ei, flag, cursor, col, E, bpx);

  k_agg<0><<<(n + 3) / 4, 256, 0, stream>>>(g1, col, rowptr, dis, b1, o1);
  k_gemm<16><<<(n + 63) / 64, 64, 0, stream>>>(o1, W2, dis, g2, n);
  k_agg<1><<<(n + 3) / 4, 256, 0, stream>>>(g2, col, rowptr, dis, b2, out);
}